// Round 2
// baseline (523.660 us; speedup 1.0000x reference)
//
#include <hip/hip_runtime.h>
#include <hip/hip_bf16.h>
#include <type_traits>

namespace {
constexpr int kB  = 2;
constexpr int kL  = 1024;
constexpr int kDM = 1024;
constexpr int kDI = 2048;
constexpr int kNH = 32;
constexpr int kDS = 64;
constexpr int kDPROJ = 2 * kDI + kNH * (2 * kDS + 1);  // 8224
constexpr int kBL = kB * kL;                            // 2048
constexpr int kQ  = 64;                                 // chunk length
constexpr int kNC = kL / kQ;                            // 16 chunks
}

typedef float f4 __attribute__((ext_vector_type(4)));
typedef __bf16 bf16x8 __attribute__((ext_vector_type(8)));

__device__ __forceinline__ void async_ld16(const void* g, void* l) {
  __builtin_amdgcn_global_load_lds(
      (const __attribute__((address_space(1))) void*)g,
      (__attribute__((address_space(3))) void*)l, 16, 0, 0);
}

// ---------------------------------------------------------------------------
// f32 -> (hi, lo) bf16 split: v = hi + lo + O(2^-17 |v|)
// ---------------------------------------------------------------------------
__global__ __launch_bounds__(256) void split_f32(
    const float* __restrict__ src, __hip_bfloat16* __restrict__ hi,
    __hip_bfloat16* __restrict__ lo, int n) {
  const int i = blockIdx.x * 256 + threadIdx.x;
  if (i >= n) return;
  const float v = src[i];
  const __hip_bfloat16 h = __float2bfloat16(v);
  hi[i] = h;
  lo[i] = __float2bfloat16(v - __bfloat162float(h));
}

__global__ __launch_bounds__(256) void cvt_f32(
    const float* __restrict__ src, __hip_bfloat16* __restrict__ dst, int n) {
  const int i = blockIdx.x * 256 + threadIdx.x;
  if (i >= n) return;
  dst[i] = __float2bfloat16(src[i]);
}

// ---------------------------------------------------------------------------
// Split GEMM: C[M,N] = (Ah+Al)[M,K] @ (Bh+Bl)[N,K]^T, bf16x3, f32 out.
// 128x128 tile, 256 threads (4 waves), BK=32, mfma_f32_16x16x32_bf16.
// ---------------------------------------------------------------------------
__global__ __launch_bounds__(256) void gemm_bt_split(
    const __hip_bfloat16* __restrict__ Ah, const __hip_bfloat16* __restrict__ Al,
    const __hip_bfloat16* __restrict__ Bh, const __hip_bfloat16* __restrict__ Bl,
    float* __restrict__ C, int M, int N, int K) {
  __shared__ alignas(16) short Ash[128][32];
  __shared__ alignas(16) short Asl[128][32];
  __shared__ alignas(16) short Bsh[128][32];
  __shared__ alignas(16) short Bsl[128][32];
  const int tid  = threadIdx.x;
  const int lane = tid & 63;
  const int w    = tid >> 6;
  const int m0   = blockIdx.x * 128;
  const int n0   = blockIdx.y * 128;
  const int ra   = lane >> 2;
  const int cc   = (lane & 3) * 8;
  const int wm   = (w & 1) * 64;
  const int wn   = (w >> 1) * 64;
  const int l16  = lane & 15;
  const int l4   = lane >> 4;

  f4 acc[4][4] = {};

  for (int k0 = 0; k0 < K; k0 += 32) {
#pragma unroll
    for (int q = 0; q < 2; ++q) {
      const int row = (w * 2 + q) * 16 + ra;
      const size_t ao = (size_t)(m0 + row) * K + (k0 + cc);
      async_ld16(Ah + ao, &Ash[row][cc]);
      async_ld16(Al + ao, &Asl[row][cc]);
      int gn = n0 + row;
      gn = gn < N ? gn : N - 1;  // clamp partial N tile (valid memory)
      const size_t bo = (size_t)gn * K + (k0 + cc);
      async_ld16(Bh + bo, &Bsh[row][cc]);
      async_ld16(Bl + bo, &Bsl[row][cc]);
    }
    __syncthreads();
    bf16x8 afh[4], afl[4], bfh[4], bfl[4];
#pragma unroll
    for (int t = 0; t < 4; ++t) {
      afh[t] = *reinterpret_cast<const bf16x8*>(&Ash[wm + t * 16 + l16][l4 * 8]);
      afl[t] = *reinterpret_cast<const bf16x8*>(&Asl[wm + t * 16 + l16][l4 * 8]);
      bfh[t] = *reinterpret_cast<const bf16x8*>(&Bsh[wn + t * 16 + l16][l4 * 8]);
      bfl[t] = *reinterpret_cast<const bf16x8*>(&Bsl[wn + t * 16 + l16][l4 * 8]);
    }
#pragma unroll
    for (int i = 0; i < 4; ++i)
#pragma unroll
      for (int j = 0; j < 4; ++j) {
        acc[i][j] = __builtin_amdgcn_mfma_f32_16x16x32_bf16(afl[i], bfh[j], acc[i][j], 0, 0, 0);
        acc[i][j] = __builtin_amdgcn_mfma_f32_16x16x32_bf16(afh[i], bfl[j], acc[i][j], 0, 0, 0);
        acc[i][j] = __builtin_amdgcn_mfma_f32_16x16x32_bf16(afh[i], bfh[j], acc[i][j], 0, 0, 0);
      }
    __syncthreads();
  }

  // C/D layout: col = lane&15, row = (lane>>4)*4 + reg
  const int col = l16;
  const int r0  = l4 * 4;
#pragma unroll
  for (int i = 0; i < 4; ++i)
#pragma unroll
    for (int j = 0; j < 4; ++j) {
      const int gn = n0 + wn + j * 16 + col;
      if (gn >= N) continue;
#pragma unroll
      for (int r = 0; r < 4; ++r) {
        const int gm = m0 + wm + i * 16 + r0 + r;
        C[(size_t)gm * N + gn] = acc[i][j][r];
      }
    }
}

// ---------------------------------------------------------------------------
// Plain bf16 GEMM: C[M,N] = A[M,K] @ B[N,K]^T (used for out-proj).
// ---------------------------------------------------------------------------
template <typename OutT>
__global__ __launch_bounds__(256) void gemm_bt(
    const __hip_bfloat16* __restrict__ A, const __hip_bfloat16* __restrict__ Bm,
    OutT* __restrict__ C, int M, int N, int K) {
  __shared__ alignas(16) short As[128][32];
  __shared__ alignas(16) short Bs[128][32];
  const int tid  = threadIdx.x;
  const int lane = tid & 63;
  const int w    = tid >> 6;
  const int m0   = blockIdx.x * 128;
  const int n0   = blockIdx.y * 128;
  const int ra   = lane >> 2;
  const int cc   = (lane & 3) * 8;
  const int wm   = (w & 1) * 64;
  const int wn   = (w >> 1) * 64;
  const int l16  = lane & 15;
  const int l4   = lane >> 4;

  f4 acc[4][4] = {};

  for (int k0 = 0; k0 < K; k0 += 32) {
#pragma unroll
    for (int q = 0; q < 2; ++q) {
      const int row = (w * 2 + q) * 16 + ra;
      async_ld16(A + (size_t)(m0 + row) * K + (k0 + cc), &As[row][cc]);
      int gn = n0 + row;
      gn = gn < N ? gn : N - 1;
      async_ld16(Bm + (size_t)gn * K + (k0 + cc), &Bs[row][cc]);
    }
    __syncthreads();
    bf16x8 af[4], bf[4];
#pragma unroll
    for (int t = 0; t < 4; ++t) {
      af[t] = *reinterpret_cast<const bf16x8*>(&As[wm + t * 16 + l16][l4 * 8]);
      bf[t] = *reinterpret_cast<const bf16x8*>(&Bs[wn + t * 16 + l16][l4 * 8]);
    }
#pragma unroll
    for (int i = 0; i < 4; ++i)
#pragma unroll
      for (int j = 0; j < 4; ++j)
        acc[i][j] = __builtin_amdgcn_mfma_f32_16x16x32_bf16(af[i], bf[j], acc[i][j], 0, 0, 0);
    __syncthreads();
  }

  const int col = l16;
  const int r0  = l4 * 4;
#pragma unroll
  for (int i = 0; i < 4; ++i)
#pragma unroll
    for (int j = 0; j < 4; ++j) {
      const int gn = n0 + wn + j * 16 + col;
      if (gn >= N) continue;
#pragma unroll
      for (int r = 0; r < 4; ++r) {
        const int gm = m0 + wm + i * 16 + r0 + r;
        const float v = acc[i][j][r];
        if constexpr (std::is_same_v<OutT, float>)
          C[(size_t)gm * N + gn] = v;
        else
          C[(size_t)gm * N + gn] = __float2bfloat16(v);
      }
    }
}

// ---------------------------------------------------------------------------
// Depthwise causal conv(4) + bias + SiLU -> xconv (f32); SiLU(z) -> zs (f32)
// ---------------------------------------------------------------------------
__global__ __launch_bounds__(256) void prep_conv(
    const float* __restrict__ proj, const float* __restrict__ conv_w,
    const float* __restrict__ conv_b, float* __restrict__ xconv,
    float* __restrict__ zs) {
  const int idx = blockIdx.x * 256 + threadIdx.x;  // [0, kBL*kDI)
  const int d   = idx & (kDI - 1);
  const int bl  = idx >> 11;
  const int l   = bl & (kL - 1);
  float acc = conv_b[d];
#pragma unroll
  for (int j = 0; j < 4; ++j) {
    const int lj = l - 3 + j;
    if (lj >= 0)
      acc += conv_w[d * 4 + j] * proj[(size_t)(bl - 3 + j) * kDPROJ + d];
  }
  xconv[idx] = acc / (1.f + __expf(-acc));
  const float z = proj[(size_t)bl * kDPROJ + kDI + d];
  zs[idx] = z / (1.f + __expf(-z));
}

// ---------------------------------------------------------------------------
// dt = softplus(dt_proj + bias); dA = exp(A*dt); dB = B*dt; Cpk = packed C
// layouts: dA/dB/Cpk [bn][l][s] (s contiguous), dtb [bn][l]
// ---------------------------------------------------------------------------
__global__ __launch_bounds__(256) void prep_scan(
    const float* __restrict__ proj, const float* __restrict__ A_log,
    const float* __restrict__ dt_bias, float* __restrict__ dA,
    float* __restrict__ dB, float* __restrict__ Cpk, float* __restrict__ dtb) {
  const int idx = blockIdx.x * 256 + threadIdx.x;  // [0, 64*kL*64)
  const int s   = idx & 63;
  const int t   = idx >> 6;  // bn*kL + l
  const int l   = t & (kL - 1);
  const int bn  = t >> 10;
  const int n   = bn & 31;
  const int b   = bn >> 5;
  const size_t prow = (size_t)(b * kL + l) * kDPROJ + 2 * kDI + n * 129;
  const float dtp = proj[prow + 128] + dt_bias[n];
  const float dt  = (dtp > 20.f) ? dtp : log1pf(__expf(dtp));
  const float Aa  = -__expf(A_log[n * 64 + s]);
  dA[idx]  = __expf(Aa * dt);
  dB[idx]  = proj[prow + s] * dt;
  Cpk[idx] = proj[prow + 64 + s];
  if (s == 0) dtb[t] = dt;
}

// ---------------------------------------------------------------------------
// Scan pass 1: per (bn, chunk) run recurrence from h=0; emit chunk-local
// final state hloc[bn][c][s][d] and sum of dt (for state closure).
// Thread layout: lane = d, wave w owns s in [16w, 16w+16).
// ---------------------------------------------------------------------------
__global__ __launch_bounds__(256) void scan_pass1(
    const float* __restrict__ dA, const float* __restrict__ dB,
    const float* __restrict__ xconv, const float* __restrict__ dtb,
    float* __restrict__ hloc, float* __restrict__ sdt) {
  const int bn   = blockIdx.x >> 4;
  const int c    = blockIdx.x & (kNC - 1);
  const int lane = threadIdx.x & 63;
  const int w    = threadIdx.x >> 6;
  const int b    = bn >> 5, n = bn & 31;
  const int l0   = c * kQ;
  const float* Ab = dA + ((size_t)bn * kL + l0) * 64 + w * 16;
  const float* Bb = dB + ((size_t)bn * kL + l0) * 64 + w * 16;
  const float* Xb = xconv + (size_t)(b * kL + l0) * kDI + n * 64 + lane;
  const float* Tb = dtb + (size_t)bn * kL + l0;

  float h[16];
#pragma unroll
  for (int j = 0; j < 16; ++j) h[j] = 0.f;
  float ssum = 0.f;

  f4 ca[4], cb[4];
  float cx, cdt;
#pragma unroll
  for (int j = 0; j < 4; ++j) {
    ca[j] = ((const f4*)Ab)[j];
    cb[j] = ((const f4*)Bb)[j];
  }
  cx  = Xb[0];
  cdt = Tb[0];

  for (int t = 0; t < kQ; ++t) {
    const int tp = (t + 1 < kQ) ? (t + 1) : (kQ - 1);
    f4 na[4], nb[4];
    float nx, ndt;
#pragma unroll
    for (int j = 0; j < 4; ++j) {
      na[j] = ((const f4*)(Ab + (size_t)tp * 64))[j];
      nb[j] = ((const f4*)(Bb + (size_t)tp * 64))[j];
    }
    nx  = Xb[(size_t)tp * kDI];
    ndt = Tb[tp];

    ssum += cdt;
#pragma unroll
    for (int q = 0; q < 4; ++q)
#pragma unroll
      for (int j = 0; j < 4; ++j)
        h[q * 4 + j] = ca[q][j] * h[q * 4 + j] + cb[q][j] * cx;

#pragma unroll
    for (int j = 0; j < 4; ++j) { ca[j] = na[j]; cb[j] = nb[j]; }
    cx = nx; cdt = ndt;
  }

  float* hp = hloc + (((size_t)bn * kNC + c) * 64 + w * 16) * 64 + lane;
#pragma unroll
  for (int j = 0; j < 16; ++j) hp[(size_t)j * 64] = h[j];
  if (threadIdx.x == 0) sdt[bn * kNC + c] = ssum;
}

// ---------------------------------------------------------------------------
// Scan pass 2: sequential chunk stitching per (bn).
// h_in[c+1] = exp(A_s * sdt[c]) * h_in[c] + hloc[c]   (exact closure)
// ---------------------------------------------------------------------------
__global__ __launch_bounds__(256) void scan_pass2(
    const float* __restrict__ hloc, const float* __restrict__ sdt,
    const float* __restrict__ A_log, float* __restrict__ hin) {
  const int bn = blockIdx.x;
  const int n  = bn & 31;
  const int s  = threadIdx.x >> 2;
  const int d0 = (threadIdx.x & 3) * 16;
  const float Aa = -__expf(A_log[n * 64 + s]);
  f4 h[4] = {};
  for (int c = 0; c < kNC; ++c) {
    const size_t off = (((size_t)bn * kNC + c) * 64 + s) * 64 + d0;
    f4* hi = (f4*)(hin + off);
    const f4* hl = (const f4*)(hloc + off);
    const float ap = __expf(Aa * sdt[bn * kNC + c]);
#pragma unroll
    for (int j = 0; j < 4; ++j) {
      hi[j] = h[j];
      h[j]  = ap * h[j] + hl[j];
    }
  }
}

// ---------------------------------------------------------------------------
// Scan pass 3: re-run chunk from correct h_in, emit y per step:
// y[d] = sum_s C[s] h[s][d];  yin = (y + D*x) * silu(z)  (bf16 for GEMM2)
// ---------------------------------------------------------------------------
__global__ __launch_bounds__(256) void scan_pass3(
    const float* __restrict__ dA, const float* __restrict__ dB,
    const float* __restrict__ Cpk, const float* __restrict__ xconv,
    const float* __restrict__ hin, const float* __restrict__ zs,
    const float* __restrict__ Dv, __hip_bfloat16* __restrict__ yin) {
  const int bn   = blockIdx.x >> 4;
  const int c    = blockIdx.x & (kNC - 1);
  const int lane = threadIdx.x & 63;
  const int w    = threadIdx.x >> 6;
  const int b    = bn >> 5, n = bn & 31;
  const int l0   = c * kQ;
  __shared__ float red[2][4][64];

  const float* Ab = dA + ((size_t)bn * kL + l0) * 64 + w * 16;
  const float* Bb = dB + ((size_t)bn * kL + l0) * 64 + w * 16;
  const float* Cb = Cpk + ((size_t)bn * kL + l0) * 64 + w * 16;
  const float* Xb = xconv + (size_t)(b * kL + l0) * kDI + n * 64 + lane;
  const float* Zb = zs + (size_t)(b * kL + l0) * kDI + n * 64 + lane;
  __hip_bfloat16* Yb = yin + (size_t)(b * kL + l0) * kDI + n * 64 + lane;
  const float Dn = Dv[n];

  float h[16];
  const float* hp = hin + (((size_t)bn * kNC + c) * 64 + w * 16) * 64 + lane;
#pragma unroll
  for (int j = 0; j < 16; ++j) h[j] = hp[(size_t)j * 64];

  f4 ca[4], cb[4], ccf[4];
  float cx;
#pragma unroll
  for (int j = 0; j < 4; ++j) {
    ca[j]  = ((const f4*)Ab)[j];
    cb[j]  = ((const f4*)Bb)[j];
    ccf[j] = ((const f4*)Cb)[j];
  }
  cx = Xb[0];

  for (int t = 0; t < kQ; ++t) {
    const int tp = (t + 1 < kQ) ? (t + 1) : (kQ - 1);
    f4 na[4], nb[4], nc[4];
    float nx;
#pragma unroll
    for (int j = 0; j < 4; ++j) {
      na[j] = ((const f4*)(Ab + (size_t)tp * 64))[j];
      nb[j] = ((const f4*)(Bb + (size_t)tp * 64))[j];
      nc[j] = ((const f4*)(Cb + (size_t)tp * 64))[j];
    }
    nx = Xb[(size_t)tp * kDI];

    float p = 0.f;
#pragma unroll
    for (int q = 0; q < 4; ++q)
#pragma unroll
      for (int j = 0; j < 4; ++j) {
        h[q * 4 + j] = ca[q][j] * h[q * 4 + j] + cb[q][j] * cx;
        p += ccf[q][j] * h[q * 4 + j];
      }
    red[t & 1][w][lane] = p;
    __syncthreads();
    if (w == 0) {
      const float y = red[t & 1][0][lane] + red[t & 1][1][lane] +
                      red[t & 1][2][lane] + red[t & 1][3][lane] + Dn * cx;
      Yb[(size_t)t * kDI] = __float2bfloat16(y * Zb[(size_t)t * kDI]);
    }
#pragma unroll
    for (int j = 0; j < 4; ++j) { ca[j] = na[j]; cb[j] = nb[j]; ccf[j] = nc[j]; }
    cx = nx;
  }
}

// ---------------------------------------------------------------------------
extern "C" void kernel_launch(void* const* d_in, const int* in_sizes, int n_in,
                              void* d_out, int out_size, void* d_ws, size_t ws_size,
                              hipStream_t stream) {
  const float* x      = (const float*)d_in[0];
  const float* W_in   = (const float*)d_in[1];
  const float* conv_w = (const float*)d_in[2];
  const float* conv_b = (const float*)d_in[3];
  const float* A_log  = (const float*)d_in[4];
  const float* Dv     = (const float*)d_in[5];
  const float* dt_b   = (const float*)d_in[6];
  const float* W_out  = (const float*)d_in[7];
  float* out = (float*)d_out;

  char* p = (char*)d_ws;
  float* proj  = (float*)p; p += (size_t)kBL * kDPROJ * 4;       // 67.4 MB
  float* xconv = (float*)p; p += (size_t)kBL * kDI * 4;          // 16.8 MB
  float* zsb   = (float*)p; p += (size_t)kBL * kDI * 4;          // 16.8 MB
  float* dtb   = (float*)p; p += (size_t)64 * kL * 4;            // 0.26 MB
  float* sdt   = (float*)p; p += (size_t)64 * kNC * 4;           // 4 KB
  float* hloc  = (float*)p; p += (size_t)64 * kNC * 64 * 64 * 4; // 16.8 MB
  float* hin   = (float*)p; p += (size_t)64 * kNC * 64 * 64 * 4; // 16.8 MB
  __hip_bfloat16* yin  = (__hip_bfloat16*)p; p += (size_t)kBL * kDI * 2;  // 8.4 MB
  __hip_bfloat16* Wo16 = (__hip_bfloat16*)p; p += (size_t)kDM * kDI * 2;  // 4.2 MB
  // union region: split inputs (GEMM1 phase) alias dA/dB/Cpk (scan phase)
  char* u = p;
  __hip_bfloat16* xhi = (__hip_bfloat16*)u;
  __hip_bfloat16* xlo = xhi + (size_t)kBL * kDM;
  __hip_bfloat16* Whi = xlo + (size_t)kBL * kDM;
  __hip_bfloat16* Wlo = Whi + (size_t)kDPROJ * kDM;
  float* dA  = (float*)u;
  float* dB  = dA + (size_t)64 * kL * 64;
  float* Cpk = dB + (size_t)64 * kL * 64;

  const int nx = kBL * kDM;          // 2.10M
  const int nw = kDPROJ * kDM;       // 8.42M
  const int no = kDM * kDI;          // 2.10M
  split_f32<<<(nx + 255) / 256, 256, 0, stream>>>(x, xhi, xlo, nx);
  split_f32<<<(nw + 255) / 256, 256, 0, stream>>>(W_in, Whi, Wlo, nw);
  cvt_f32<<<(no + 255) / 256, 256, 0, stream>>>(W_out, Wo16, no);

  gemm_bt_split<<<dim3(kBL / 128, (kDPROJ + 127) / 128), 256, 0, stream>>>(
      xhi, xlo, Whi, Wlo, proj, kBL, kDPROJ, kDM);

  prep_conv<<<(kBL * kDI) / 256, 256, 0, stream>>>(proj, conv_w, conv_b, xconv, zsb);
  prep_scan<<<(64 * kL * 64) / 256, 256, 0, stream>>>(proj, A_log, dt_b, dA, dB, Cpk, dtb);
  scan_pass1<<<64 * kNC, 256, 0, stream>>>(dA, dB, xconv, dtb, hloc, sdt);
  scan_pass2<<<64, 256, 0, stream>>>(hloc, sdt, A_log, hin);
  scan_pass3<<<64 * kNC, 256, 0, stream>>>(dA, dB, Cpk, xconv, hin, zsb, Dv, yin);

  gemm_bt<float><<<dim3(kBL / 128, kDM / 128), 256, 0, stream>>>(
      yin, Wo16, out, kBL, kDM, kDI);
}

// Round 3
// 427.162 us; speedup vs baseline: 1.2259x; 1.2259x over previous
//
#include <hip/hip_runtime.h>
#include <hip/hip_fp16.h>

namespace {
constexpr int kB  = 2;
constexpr int kL  = 1024;
constexpr int kDM = 1024;
constexpr int kDI = 2048;
constexpr int kDPROJ = 2 * kDI + 32 * (2 * 64 + 1);  // 8224
constexpr int kBL = kB * kL;                          // 2048
constexpr int kQ  = 64;                               // chunk length
constexpr int kNC = kL / kQ;                          // 16 chunks
}

typedef float f4 __attribute__((ext_vector_type(4)));
typedef _Float16 f16x8 __attribute__((ext_vector_type(8)));
typedef _Float16 f16x4 __attribute__((ext_vector_type(4)));

__device__ __forceinline__ void async_ld16(const void* g, void* l) {
  __builtin_amdgcn_global_load_lds(
      (const __attribute__((address_space(1))) void*)g,
      (__attribute__((address_space(3))) void*)l, 16, 0, 0);
}

// ---------------------------------------------------------------------------
// Fused f32 -> f16 conversion of x, W_in, W_out (vectorized x4)
// ---------------------------------------------------------------------------
__global__ __launch_bounds__(256) void cvt_all(
    const float* __restrict__ s0, _Float16* __restrict__ d0, int n0,
    const float* __restrict__ s1, _Float16* __restrict__ d1, int n1,
    const float* __restrict__ s2, _Float16* __restrict__ d2, int n2) {
  int i = blockIdx.x * 256 + threadIdx.x;  // vec4 index
  const float* s; _Float16* d;
  if (i < n0) { s = s0; d = d0; }
  else if (i < n0 + n1) { s = s1; d = d1; i -= n0; }
  else if (i < n0 + n1 + n2) { s = s2; d = d2; i -= n0 + n1; }
  else return;
  const f4 v = ((const f4*)s)[i];
  f16x4 o;
  o[0] = (_Float16)v[0]; o[1] = (_Float16)v[1];
  o[2] = (_Float16)v[2]; o[3] = (_Float16)v[3];
  ((f16x4*)d)[i] = o;
}

// ---------------------------------------------------------------------------
// f16 GEMM: C[M,N](f32) = A[M,*] @ B[N,*]^T over K columns starting at
// blockIdx.z*K (split-K; partial written to C + z*M*N).
// 128x128 tile, 256 threads (4 waves), BK=32, mfma_f32_16x16x32_f16.
// ---------------------------------------------------------------------------
__global__ __launch_bounds__(256) void gemm_bt16(
    const _Float16* __restrict__ A, const _Float16* __restrict__ Bm,
    float* __restrict__ C, int M, int N, int K, int lda, int ldb) {
  __shared__ alignas(16) _Float16 As[128][32];
  __shared__ alignas(16) _Float16 Bs[128][32];
  const int tid  = threadIdx.x;
  const int lane = tid & 63;
  const int w    = tid >> 6;
  const int m0   = blockIdx.x * 128;
  const int n0   = blockIdx.y * 128;
  const int ra   = lane >> 2;
  const int cc   = (lane & 3) * 8;
  const int wm   = (w & 1) * 64;
  const int wn   = (w >> 1) * 64;
  const int l16  = lane & 15;
  const int l4   = lane >> 4;

  A += (size_t)blockIdx.z * K;          // split-K slice
  Bm += (size_t)blockIdx.z * K;
  C += (size_t)blockIdx.z * M * N;

  f4 acc[4][4] = {};

  for (int k0 = 0; k0 < K; k0 += 32) {
#pragma unroll
    for (int q = 0; q < 2; ++q) {
      const int row = (w * 2 + q) * 16 + ra;
      async_ld16(A + (size_t)(m0 + row) * lda + (k0 + cc), &As[row][cc]);
      int gn = n0 + row;
      gn = gn < N ? gn : N - 1;  // clamp partial N tile (valid memory)
      async_ld16(Bm + (size_t)gn * ldb + (k0 + cc), &Bs[row][cc]);
    }
    __syncthreads();
    f16x8 af[4], bf[4];
#pragma unroll
    for (int t = 0; t < 4; ++t) {
      af[t] = *reinterpret_cast<const f16x8*>(&As[wm + t * 16 + l16][l4 * 8]);
      bf[t] = *reinterpret_cast<const f16x8*>(&Bs[wn + t * 16 + l16][l4 * 8]);
    }
#pragma unroll
    for (int i = 0; i < 4; ++i)
#pragma unroll
      for (int j = 0; j < 4; ++j)
        acc[i][j] = __builtin_amdgcn_mfma_f32_16x16x32_f16(af[i], bf[j], acc[i][j], 0, 0, 0);
    __syncthreads();
  }

  // C/D layout: col = lane&15, row = (lane>>4)*4 + reg
  const int col = l16;
  const int r0  = l4 * 4;
#pragma unroll
  for (int i = 0; i < 4; ++i)
#pragma unroll
    for (int j = 0; j < 4; ++j) {
      const int gn = n0 + wn + j * 16 + col;
      if (gn >= N) continue;
#pragma unroll
      for (int r = 0; r < 4; ++r) {
        const int gm = m0 + wm + i * 16 + r0 + r;
        C[(size_t)gm * N + gn] = acc[i][j][r];
      }
    }
}

// ---------------------------------------------------------------------------
// out = p0 + p1 + p2 + p3 (split-K reduction), vectorized x4
// ---------------------------------------------------------------------------
__global__ __launch_bounds__(256) void add4(
    const float* __restrict__ parts, float* __restrict__ out, int n4) {
  const int i = blockIdx.x * 256 + threadIdx.x;
  if (i >= n4) return;
  const size_t mn4 = (size_t)kBL * kDM / 4;
  const f4* p = (const f4*)parts;
  const f4 v = p[i] + p[i + mn4] + p[i + 2 * mn4] + p[i + 3 * mn4];
  ((f4*)out)[i] = v;
}

// ---------------------------------------------------------------------------
// Depthwise causal conv(4) + bias + SiLU -> xconv (f32); SiLU(z) -> zs (f32)
// ---------------------------------------------------------------------------
__global__ __launch_bounds__(256) void prep_conv(
    const float* __restrict__ proj, const float* __restrict__ conv_w,
    const float* __restrict__ conv_b, float* __restrict__ xconv,
    float* __restrict__ zs) {
  const int idx = blockIdx.x * 256 + threadIdx.x;  // [0, kBL*kDI)
  const int d   = idx & (kDI - 1);
  const int bl  = idx >> 11;
  const int l   = bl & (kL - 1);
  float acc = conv_b[d];
#pragma unroll
  for (int j = 0; j < 4; ++j) {
    const int lj = l - 3 + j;
    if (lj >= 0)
      acc += conv_w[d * 4 + j] * proj[(size_t)(bl - 3 + j) * kDPROJ + d];
  }
  xconv[idx] = acc / (1.f + __expf(-acc));
  const float z = proj[(size_t)bl * kDPROJ + kDI + d];
  zs[idx] = z / (1.f + __expf(-z));
}

// ---------------------------------------------------------------------------
// dt = softplus(dt_proj + bias); dA = exp(A*dt); dB = B*dt; Cpk = packed C
// layouts: dA/dB/Cpk [bn][l][s] (s contiguous), dtb [bn][l]
// ---------------------------------------------------------------------------
__global__ __launch_bounds__(256) void prep_scan(
    const float* __restrict__ proj, const float* __restrict__ A_log,
    const float* __restrict__ dt_bias, float* __restrict__ dA,
    float* __restrict__ dB, float* __restrict__ Cpk, float* __restrict__ dtb) {
  const int idx = blockIdx.x * 256 + threadIdx.x;  // [0, 64*kL*64)
  const int s   = idx & 63;
  const int t   = idx >> 6;  // bn*kL + l
  const int l   = t & (kL - 1);
  const int bn  = t >> 10;
  const int n   = bn & 31;
  const int b   = bn >> 5;
  const size_t prow = (size_t)(b * kL + l) * kDPROJ + 2 * kDI + n * 129;
  const float dtp = proj[prow + 128] + dt_bias[n];
  const float dt  = (dtp > 20.f) ? dtp : log1pf(__expf(dtp));
  const float Aa  = -__expf(A_log[n * 64 + s]);
  dA[idx]  = __expf(Aa * dt);
  dB[idx]  = proj[prow + s] * dt;
  Cpk[idx] = proj[prow + 64 + s];
  if (s == 0) dtb[t] = dt;
}

// ---------------------------------------------------------------------------
// Scan pass 1: per (bn, chunk) run recurrence from h=0; emit chunk-local
// final state hloc[bn][c][s][d] and sum of dt (for state closure).
// Thread layout: lane = d, wave w owns s in [16w, 16w+16).
// ---------------------------------------------------------------------------
__global__ __launch_bounds__(256) void scan_pass1(
    const float* __restrict__ dA, const float* __restrict__ dB,
    const float* __restrict__ xconv, const float* __restrict__ dtb,
    float* __restrict__ hloc, float* __restrict__ sdt) {
  const int bn   = blockIdx.x >> 4;
  const int c    = blockIdx.x & (kNC - 1);
  const int lane = threadIdx.x & 63;
  const int w    = threadIdx.x >> 6;
  const int b    = bn >> 5, n = bn & 31;
  const int l0   = c * kQ;
  const float* Ab = dA + ((size_t)bn * kL + l0) * 64 + w * 16;
  const float* Bb = dB + ((size_t)bn * kL + l0) * 64 + w * 16;
  const float* Xb = xconv + (size_t)(b * kL + l0) * kDI + n * 64 + lane;
  const float* Tb = dtb + (size_t)bn * kL + l0;

  float h[16];
#pragma unroll
  for (int j = 0; j < 16; ++j) h[j] = 0.f;
  float ssum = 0.f;

  f4 ca[4], cb[4];
  float cx, cdt;
#pragma unroll
  for (int j = 0; j < 4; ++j) {
    ca[j] = ((const f4*)Ab)[j];
    cb[j] = ((const f4*)Bb)[j];
  }
  cx  = Xb[0];
  cdt = Tb[0];

  for (int t = 0; t < kQ; ++t) {
    const int tp = (t + 1 < kQ) ? (t + 1) : (kQ - 1);
    f4 na[4], nb[4];
    float nx, ndt;
#pragma unroll
    for (int j = 0; j < 4; ++j) {
      na[j] = ((const f4*)(Ab + (size_t)tp * 64))[j];
      nb[j] = ((const f4*)(Bb + (size_t)tp * 64))[j];
    }
    nx  = Xb[(size_t)tp * kDI];
    ndt = Tb[tp];

    ssum += cdt;
#pragma unroll
    for (int q = 0; q < 4; ++q)
#pragma unroll
      for (int j = 0; j < 4; ++j)
        h[q * 4 + j] = ca[q][j] * h[q * 4 + j] + cb[q][j] * cx;

#pragma unroll
    for (int j = 0; j < 4; ++j) { ca[j] = na[j]; cb[j] = nb[j]; }
    cx = nx; cdt = ndt;
  }

  float* hp = hloc + (((size_t)bn * kNC + c) * 64 + w * 16) * 64 + lane;
#pragma unroll
  for (int j = 0; j < 16; ++j) hp[(size_t)j * 64] = h[j];
  if (threadIdx.x == 0) sdt[bn * kNC + c] = ssum;
}

// ---------------------------------------------------------------------------
// Scan pass 2: sequential chunk stitching per (bn).
// h_in[c+1] = exp(A_s * sdt[c]) * h_in[c] + hloc[c]   (exact closure)
// ---------------------------------------------------------------------------
__global__ __launch_bounds__(256) void scan_pass2(
    const float* __restrict__ hloc, const float* __restrict__ sdt,
    const float* __restrict__ A_log, float* __restrict__ hin) {
  const int bn = blockIdx.x;
  const int n  = bn & 31;
  const int s  = threadIdx.x >> 2;
  const int d0 = (threadIdx.x & 3) * 16;
  const float Aa = -__expf(A_log[n * 64 + s]);
  f4 h[4] = {};
  for (int c = 0; c < kNC; ++c) {
    const size_t off = (((size_t)bn * kNC + c) * 64 + s) * 64 + d0;
    f4* hi = (f4*)(hin + off);
    const f4* hl = (const f4*)(hloc + off);
    const float ap = __expf(Aa * sdt[bn * kNC + c]);
#pragma unroll
    for (int j = 0; j < 4; ++j) {
      hi[j] = h[j];
      h[j]  = ap * h[j] + hl[j];
    }
  }
}

// ---------------------------------------------------------------------------
// Scan pass 3 (barrier-free): lanes = (sg, dd): sg = s-group (4x16), dd = d
// within the wave's 16-d slice. s-reduction via 2x shfl_xor, no LDS.
// y[d] = sum_s C[s] h[s][d]; yin = (y + D*x) * silu(z)  (f16 for GEMM2)
// ---------------------------------------------------------------------------
__global__ __launch_bounds__(256) void scan_pass3(
    const float* __restrict__ dA, const float* __restrict__ dB,
    const float* __restrict__ Cpk, const float* __restrict__ xconv,
    const float* __restrict__ hin, const float* __restrict__ zs,
    const float* __restrict__ Dv, _Float16* __restrict__ yin) {
  const int bn   = blockIdx.x >> 4;
  const int c    = blockIdx.x & (kNC - 1);
  const int lane = threadIdx.x & 63;
  const int w    = threadIdx.x >> 6;  // d-group: d = w*16 + dd
  const int sg   = lane >> 4;         // s-group: s in [16sg, 16sg+16)
  const int dd   = lane & 15;
  const int b    = bn >> 5, n = bn & 31;
  const int l0   = c * kQ;
  const int d    = w * 16 + dd;

  const float* Ab = dA + ((size_t)bn * kL + l0) * 64 + sg * 16;
  const float* Bb = dB + ((size_t)bn * kL + l0) * 64 + sg * 16;
  const float* Cb = Cpk + ((size_t)bn * kL + l0) * 64 + sg * 16;
  const float* Xb = xconv + (size_t)(b * kL + l0) * kDI + n * 64 + d;
  const float* Zb = zs + (size_t)(b * kL + l0) * kDI + n * 64 + d;
  _Float16* Yb = yin + (size_t)(b * kL + l0) * kDI + n * 64 + d;
  const float Dn = Dv[n];

  float h[16];
  const float* hp = hin + (((size_t)bn * kNC + c) * 64 + sg * 16) * 64 + d;
#pragma unroll
  for (int j = 0; j < 16; ++j) h[j] = hp[(size_t)j * 64];

  f4 ca[4], cb[4], cc4[4];
  float cx, cz;
#pragma unroll
  for (int j = 0; j < 4; ++j) {
    ca[j]  = ((const f4*)Ab)[j];
    cb[j]  = ((const f4*)Bb)[j];
    cc4[j] = ((const f4*)Cb)[j];
  }
  cx = Xb[0];
  cz = Zb[0];

  for (int t = 0; t < kQ; ++t) {
    const int tp = (t + 1 < kQ) ? (t + 1) : (kQ - 1);
    f4 na[4], nb[4], nc[4];
#pragma unroll
    for (int j = 0; j < 4; ++j) {
      na[j] = ((const f4*)(Ab + (size_t)tp * 64))[j];
      nb[j] = ((const f4*)(Bb + (size_t)tp * 64))[j];
      nc[j] = ((const f4*)(Cb + (size_t)tp * 64))[j];
    }
    const float nx = Xb[(size_t)tp * kDI];
    const float nz = Zb[(size_t)tp * kDI];

    float p = 0.f;
#pragma unroll
    for (int q = 0; q < 4; ++q)
#pragma unroll
      for (int j = 0; j < 4; ++j) {
        h[q * 4 + j] = ca[q][j] * h[q * 4 + j] + cb[q][j] * cx;
        p += cc4[q][j] * h[q * 4 + j];
      }
    p += __shfl_xor(p, 16);
    p += __shfl_xor(p, 32);
    if (sg == 0)
      Yb[(size_t)t * kDI] = (_Float16)((p + Dn * cx) * cz);

#pragma unroll
    for (int j = 0; j < 4; ++j) { ca[j] = na[j]; cb[j] = nb[j]; cc4[j] = nc[j]; }
    cx = nx; cz = nz;
  }
}

// ---------------------------------------------------------------------------
extern "C" void kernel_launch(void* const* d_in, const int* in_sizes, int n_in,
                              void* d_out, int out_size, void* d_ws, size_t ws_size,
                              hipStream_t stream) {
  const float* x      = (const float*)d_in[0];
  const float* W_in   = (const float*)d_in[1];
  const float* conv_w = (const float*)d_in[2];
  const float* conv_b = (const float*)d_in[3];
  const float* A_log  = (const float*)d_in[4];
  const float* Dv     = (const float*)d_in[5];
  const float* dt_b   = (const float*)d_in[6];
  const float* W_out  = (const float*)d_in[7];
  float* out = (float*)d_out;

  char* p = (char*)d_ws;
  float* proj  = (float*)p; p += (size_t)kBL * kDPROJ * 4;       // 67.4 MB
  float* xconv = (float*)p; p += (size_t)kBL * kDI * 4;          // 16.8 MB
  float* zsb   = (float*)p; p += (size_t)kBL * kDI * 4;          // 16.8 MB
  float* dtb   = (float*)p; p += (size_t)64 * kL * 4;            // 0.26 MB
  float* sdt   = (float*)p; p += (size_t)64 * kNC * 4 + 4032;    // pad to 16B
  float* hloc  = (float*)p; p += (size_t)64 * kNC * 64 * 64 * 4; // 16.8 MB
  float* hin   = (float*)p; p += (size_t)64 * kNC * 64 * 64 * 4; // 16.8 MB
  _Float16* yin  = (_Float16*)p; p += (size_t)kBL * kDI * 2;     // 8.4 MB
  _Float16* Wo16 = (_Float16*)p; p += (size_t)kDM * kDI * 2;     // 4.2 MB
  // union 1: x16/Wi16 (GEMM1 phase) alias hloc+hin (scan phase)
  _Float16* x16  = (_Float16*)hloc;                  // 4.2 MB
  _Float16* Wi16 = x16 + (size_t)kBL * kDM;          // 16.8 MB (spills into hin)
  // union 2: dA/dB/Cpk (scan phase) alias split-K partials (GEMM2 phase)
  char* u = p;
  float* dA  = (float*)u;
  float* dB  = dA + (size_t)64 * kL * 64;
  float* Cpk = dB + (size_t)64 * kL * 64;            // trio = 50.3 MB
  float* parts = (float*)u;                          // 4 x 8.4 = 33.6 MB

  const int n0 = kBL * kDM / 4;     // x      vec4 count
  const int n1 = kDPROJ * kDM / 4;  // W_in
  const int n2 = kDM * kDI / 4;     // W_out
  cvt_all<<<(n0 + n1 + n2 + 255) / 256, 256, 0, stream>>>(
      x, x16, n0, W_in, Wi16, n1, W_out, Wo16, n2);

  gemm_bt16<<<dim3(kBL / 128, (kDPROJ + 127) / 128, 1), 256, 0, stream>>>(
      x16, Wi16, proj, kBL, kDPROJ, kDM, kDM, kDM);

  prep_conv<<<(kBL * kDI) / 256, 256, 0, stream>>>(proj, conv_w, conv_b, xconv, zsb);
  prep_scan<<<(64 * kL * 64) / 256, 256, 0, stream>>>(proj, A_log, dt_b, dA, dB, Cpk, dtb);
  scan_pass1<<<64 * kNC, 256, 0, stream>>>(dA, dB, xconv, dtb, hloc, sdt);
  scan_pass2<<<64, 256, 0, stream>>>(hloc, sdt, A_log, hin);
  scan_pass3<<<64 * kNC, 256, 0, stream>>>(dA, dB, Cpk, xconv, hin, zsb, Dv, yin);

  // GEMM2 split-K=4: 512 blocks (2/CU), then reduce
  gemm_bt16<<<dim3(kBL / 128, kDM / 128, 4), 256, 0, stream>>>(
      yin, Wo16, parts, kBL, kDM, kDI / 4, kDI, kDI);
  add4<<<(kBL * kDM / 4 + 255) / 256, 256, 0, stream>>>(parts, out, kBL * kDM / 4);
}

// Round 4
// 330.512 us; speedup vs baseline: 1.5844x; 1.2924x over previous
//
#include <hip/hip_runtime.h>
#include <hip/hip_fp16.h>

namespace {
constexpr int kB  = 2;
constexpr int kL  = 1024;
constexpr int kDM = 1024;
constexpr int kDI = 2048;
constexpr int kDPROJ = 2 * kDI + 32 * (2 * 64 + 1);  // 8224
constexpr int kBL = kB * kL;                          // 2048
constexpr int kQ  = 64;                               // chunk length
constexpr int kNC = kL / kQ;                          // 16 chunks
}

typedef float f4 __attribute__((ext_vector_type(4)));
typedef _Float16 f16x8 __attribute__((ext_vector_type(8)));
typedef _Float16 f16x4 __attribute__((ext_vector_type(4)));

__device__ __forceinline__ void async_ld16(const void* g, void* l) {
  __builtin_amdgcn_global_load_lds(
      (const __attribute__((address_space(1))) void*)g,
      (__attribute__((address_space(3))) void*)l, 16, 0, 0);
}

// ---------------------------------------------------------------------------
// Fused f32 -> f16 conversion of x, W_in, W_out (vectorized x4)
// ---------------------------------------------------------------------------
__global__ __launch_bounds__(256) void cvt_all(
    const float* __restrict__ s0, _Float16* __restrict__ d0, int n0,
    const float* __restrict__ s1, _Float16* __restrict__ d1, int n1,
    const float* __restrict__ s2, _Float16* __restrict__ d2, int n2) {
  int i = blockIdx.x * 256 + threadIdx.x;  // vec4 index
  const float* s; _Float16* d;
  if (i < n0) { s = s0; d = d0; }
  else if (i < n0 + n1) { s = s1; d = d1; i -= n0; }
  else if (i < n0 + n1 + n2) { s = s2; d = d2; i -= n0 + n1; }
  else return;
  const f4 v = ((const f4*)s)[i];
  f16x4 o;
  o[0] = (_Float16)v[0]; o[1] = (_Float16)v[1];
  o[2] = (_Float16)v[2]; o[3] = (_Float16)v[3];
  ((f16x4*)d)[i] = o;
}

// ---------------------------------------------------------------------------
// f16 GEMM: C[M,N](f32) = A[M,*] @ B[N,*]^T over K columns starting at
// blockIdx.z*K (split-K; partial written to C + z*M*N).
// 128x128 tile, 256 threads (4 waves), BK=32, mfma_f32_16x16x32_f16.
// ---------------------------------------------------------------------------
__global__ __launch_bounds__(256) void gemm_bt16(
    const _Float16* __restrict__ A, const _Float16* __restrict__ Bm,
    float* __restrict__ C, int M, int N, int K, int lda, int ldb) {
  __shared__ alignas(16) _Float16 As[128][32];
  __shared__ alignas(16) _Float16 Bs[128][32];
  const int tid  = threadIdx.x;
  const int lane = tid & 63;
  const int w    = tid >> 6;
  const int m0   = blockIdx.x * 128;
  const int n0   = blockIdx.y * 128;
  const int ra   = lane >> 2;
  const int cc   = (lane & 3) * 8;
  const int wm   = (w & 1) * 64;
  const int wn   = (w >> 1) * 64;
  const int l16  = lane & 15;
  const int l4   = lane >> 4;

  A += (size_t)blockIdx.z * K;          // split-K slice
  Bm += (size_t)blockIdx.z * K;
  C += (size_t)blockIdx.z * M * N;

  f4 acc[4][4] = {};

  for (int k0 = 0; k0 < K; k0 += 32) {
#pragma unroll
    for (int q = 0; q < 2; ++q) {
      const int row = (w * 2 + q) * 16 + ra;
      async_ld16(A + (size_t)(m0 + row) * lda + (k0 + cc), &As[row][cc]);
      int gn = n0 + row;
      gn = gn < N ? gn : N - 1;  // clamp partial N tile (valid memory)
      async_ld16(Bm + (size_t)gn * ldb + (k0 + cc), &Bs[row][cc]);
    }
    __syncthreads();
    f16x8 af[4], bf[4];
#pragma unroll
    for (int t = 0; t < 4; ++t) {
      af[t] = *reinterpret_cast<const f16x8*>(&As[wm + t * 16 + l16][l4 * 8]);
      bf[t] = *reinterpret_cast<const f16x8*>(&Bs[wn + t * 16 + l16][l4 * 8]);
    }
#pragma unroll
    for (int i = 0; i < 4; ++i)
#pragma unroll
      for (int j = 0; j < 4; ++j)
        acc[i][j] = __builtin_amdgcn_mfma_f32_16x16x32_f16(af[i], bf[j], acc[i][j], 0, 0, 0);
    __syncthreads();
  }

  // C/D layout: col = lane&15, row = (lane>>4)*4 + reg
  const int col = l16;
  const int r0  = l4 * 4;
#pragma unroll
  for (int i = 0; i < 4; ++i)
#pragma unroll
    for (int j = 0; j < 4; ++j) {
      const int gn = n0 + wn + j * 16 + col;
      if (gn >= N) continue;
#pragma unroll
      for (int r = 0; r < 4; ++r) {
        const int gm = m0 + wm + i * 16 + r0 + r;
        C[(size_t)gm * N + gn] = acc[i][j][r];
      }
    }
}

// ---------------------------------------------------------------------------
// out = p0 + p1 + p2 + p3 (split-K reduction), vectorized x4
// ---------------------------------------------------------------------------
__global__ __launch_bounds__(256) void add4(
    const float* __restrict__ parts, float* __restrict__ out, int n4) {
  const int i = blockIdx.x * 256 + threadIdx.x;
  if (i >= n4) return;
  const size_t mn4 = (size_t)kBL * kDM / 4;
  const f4* p = (const f4*)parts;
  const f4 v = p[i] + p[i + mn4] + p[i + 2 * mn4] + p[i + 3 * mn4];
  ((f4*)out)[i] = v;
}

// ---------------------------------------------------------------------------
// Depthwise causal conv(4) + bias + SiLU -> xconv (f32); SiLU(z) -> zs (f32)
// ---------------------------------------------------------------------------
__global__ __launch_bounds__(256) void prep_conv(
    const float* __restrict__ proj, const float* __restrict__ conv_w,
    const float* __restrict__ conv_b, float* __restrict__ xconv,
    float* __restrict__ zs) {
  const int idx = blockIdx.x * 256 + threadIdx.x;  // [0, kBL*kDI)
  const int d   = idx & (kDI - 1);
  const int bl  = idx >> 11;
  const int l   = bl & (kL - 1);
  float acc = conv_b[d];
#pragma unroll
  for (int j = 0; j < 4; ++j) {
    const int lj = l - 3 + j;
    if (lj >= 0)
      acc += conv_w[d * 4 + j] * proj[(size_t)(bl - 3 + j) * kDPROJ + d];
  }
  xconv[idx] = acc / (1.f + __expf(-acc));
  const float z = proj[(size_t)bl * kDPROJ + kDI + d];
  zs[idx] = z / (1.f + __expf(-z));
}

// ---------------------------------------------------------------------------
// dt = softplus(dt_proj + bias); dA = exp(A*dt); dB = B*dt; Cpk = packed C
// layouts: dA/dB/Cpk [bn][l][s] (s contiguous), dtb [bn][l]
// ---------------------------------------------------------------------------
__global__ __launch_bounds__(256) void prep_scan(
    const float* __restrict__ proj, const float* __restrict__ A_log,
    const float* __restrict__ dt_bias, float* __restrict__ dA,
    float* __restrict__ dB, float* __restrict__ Cpk, float* __restrict__ dtb) {
  const int idx = blockIdx.x * 256 + threadIdx.x;  // [0, 64*kL*64)
  const int s   = idx & 63;
  const int t   = idx >> 6;  // bn*kL + l
  const int l   = t & (kL - 1);
  const int bn  = t >> 10;
  const int n   = bn & 31;
  const int b   = bn >> 5;
  const size_t prow = (size_t)(b * kL + l) * kDPROJ + 2 * kDI + n * 129;
  const float dtp = proj[prow + 128] + dt_bias[n];
  const float dt  = (dtp > 20.f) ? dtp : log1pf(__expf(dtp));
  const float Aa  = -__expf(A_log[n * 64 + s]);
  dA[idx]  = __expf(Aa * dt);
  dB[idx]  = proj[prow + s] * dt;
  Cpk[idx] = proj[prow + 64 + s];
  if (s == 0) dtb[t] = dt;
}

// ---------------------------------------------------------------------------
// Scan pass 1 (LDS-staged): stage chunk dA/dB/x into LDS once, then run the
// 64-step recurrence from LDS. lane = d, wave w owns s in [16w, 16w+16).
// Emits hloc[bn][c][s][d] and sdt (chunk dt sum).
// ---------------------------------------------------------------------------
__global__ __launch_bounds__(256) void scan_pass1(
    const float* __restrict__ dA, const float* __restrict__ dB,
    const float* __restrict__ xconv, const float* __restrict__ dtb,
    float* __restrict__ hloc, float* __restrict__ sdt) {
  __shared__ alignas(16) float Ad[kQ][64];   // 16 KB
  __shared__ alignas(16) float Bd[kQ][64];   // 16 KB
  __shared__ alignas(16) float Xd[kQ][64];   // 16 KB
  __shared__ alignas(16) float dts[kQ];      // 256 B
  const int tid  = threadIdx.x;
  const int bn   = blockIdx.x >> 4;
  const int c    = blockIdx.x & (kNC - 1);
  const int lane = tid & 63;
  const int w    = tid >> 6;
  const int b    = bn >> 5, n = bn & 31;
  const int l0   = c * kQ;

  // --- stage: dA/dB are fully contiguous 16 KB slabs; x is 64x256B rows ---
  const float* gA = dA + ((size_t)bn * kL + l0) * 64;
  const float* gB = dB + ((size_t)bn * kL + l0) * 64;
#pragma unroll
  for (int i = 0; i < 4; ++i) {
    async_ld16(gA + i * 1024 + tid * 4, &Ad[0][0] + i * 1024 + tid * 4);
    async_ld16(gB + i * 1024 + tid * 4, &Bd[0][0] + i * 1024 + tid * 4);
  }
  const int tr = tid >> 4;         // row within 16-row group
  const int tc = (tid & 15) * 4;   // float offset within row
#pragma unroll
  for (int i = 0; i < 4; ++i) {
    const int t = i * 16 + tr;
    async_ld16(xconv + (size_t)(b * kL + l0 + t) * kDI + n * 64 + tc, &Xd[t][tc]);
  }
  if (tid < 16) async_ld16(dtb + (size_t)bn * kL + l0 + tid * 4, &dts[tid * 4]);
  __syncthreads();

  if (tid == 0) {
    float s = 0.f;
    for (int t = 0; t < kQ; ++t) s += dts[t];
    sdt[bn * kNC + c] = s;
  }

  float h[16];
#pragma unroll
  for (int j = 0; j < 16; ++j) h[j] = 0.f;

#pragma unroll 4
  for (int t = 0; t < kQ; ++t) {
    f4 a[4], bb[4];
#pragma unroll
    for (int j = 0; j < 4; ++j) {
      a[j]  = ((const f4*)&Ad[t][w * 16])[j];
      bb[j] = ((const f4*)&Bd[t][w * 16])[j];
    }
    const float xt = Xd[t][lane];
#pragma unroll
    for (int q = 0; q < 4; ++q)
#pragma unroll
      for (int j = 0; j < 4; ++j)
        h[q * 4 + j] = a[q][j] * h[q * 4 + j] + bb[q][j] * xt;
  }

  float* hp = hloc + (((size_t)bn * kNC + c) * 64 + w * 16) * 64 + lane;
#pragma unroll
  for (int j = 0; j < 16; ++j) hp[(size_t)j * 64] = h[j];
}

// ---------------------------------------------------------------------------
// Scan pass 2: sequential chunk stitching per (bn).
// h_in[c+1] = exp(A_s * sdt[c]) * h_in[c] + hloc[c]   (exact closure)
// ---------------------------------------------------------------------------
__global__ __launch_bounds__(256) void scan_pass2(
    const float* __restrict__ hloc, const float* __restrict__ sdt,
    const float* __restrict__ A_log, float* __restrict__ hin) {
  const int bn = blockIdx.x;
  const int n  = bn & 31;
  const int s  = threadIdx.x >> 2;
  const int d0 = (threadIdx.x & 3) * 16;
  const float Aa = -__expf(A_log[n * 64 + s]);
  f4 h[4] = {};
  for (int c = 0; c < kNC; ++c) {
    const size_t off = (((size_t)bn * kNC + c) * 64 + s) * 64 + d0;
    f4* hi = (f4*)(hin + off);
    const f4* hl = (const f4*)(hloc + off);
    const float ap = __expf(Aa * sdt[bn * kNC + c]);
#pragma unroll
    for (int j = 0; j < 4; ++j) {
      hi[j] = h[j];
      h[j]  = ap * h[j] + hl[j];
    }
  }
}

// ---------------------------------------------------------------------------
// Scan pass 3 (LDS-staged, barrier-free reduce): stage chunk dA/dB/C/x into
// LDS, run recurrence from correct h_in, per step reduce over s via shfl.
// lanes = (sg, dd): sg = s-group (4x16), dd = d; d = w*16 + dd.
// yin = (y + D*x) * silu(z)  (f16 for GEMM2)
// ---------------------------------------------------------------------------
__global__ __launch_bounds__(256) void scan_pass3(
    const float* __restrict__ dA, const float* __restrict__ dB,
    const float* __restrict__ Cpk, const float* __restrict__ xconv,
    const float* __restrict__ hin, const float* __restrict__ zs,
    const float* __restrict__ Dv, _Float16* __restrict__ yin) {
  __shared__ alignas(16) float Ad[kQ][64];   // 16 KB
  __shared__ alignas(16) float Bd[kQ][64];   // 16 KB
  __shared__ alignas(16) float Cd[kQ][64];   // 16 KB
  __shared__ alignas(16) float Xd[kQ][64];   // 16 KB
  const int tid  = threadIdx.x;
  const int bn   = blockIdx.x >> 4;
  const int c    = blockIdx.x & (kNC - 1);
  const int lane = tid & 63;
  const int w    = tid >> 6;          // d-group
  const int sg   = lane >> 4;         // s-group
  const int dd   = lane & 15;
  const int b    = bn >> 5, n = bn & 31;
  const int l0   = c * kQ;
  const int d    = w * 16 + dd;

  // --- stage ---
  const float* gA = dA + ((size_t)bn * kL + l0) * 64;
  const float* gB = dB + ((size_t)bn * kL + l0) * 64;
  const float* gC = Cpk + ((size_t)bn * kL + l0) * 64;
#pragma unroll
  for (int i = 0; i < 4; ++i) {
    async_ld16(gA + i * 1024 + tid * 4, &Ad[0][0] + i * 1024 + tid * 4);
    async_ld16(gB + i * 1024 + tid * 4, &Bd[0][0] + i * 1024 + tid * 4);
    async_ld16(gC + i * 1024 + tid * 4, &Cd[0][0] + i * 1024 + tid * 4);
  }
  const int tr = tid >> 4;
  const int tc = (tid & 15) * 4;
#pragma unroll
  for (int i = 0; i < 4; ++i) {
    const int t = i * 16 + tr;
    async_ld16(xconv + (size_t)(b * kL + l0 + t) * kDI + n * 64 + tc, &Xd[t][tc]);
  }

  // h init (global, off the steady-state path)
  float h[16];
  const float* hp = hin + (((size_t)bn * kNC + c) * 64 + sg * 16) * 64 + d;
#pragma unroll
  for (int j = 0; j < 16; ++j) h[j] = hp[(size_t)j * 64];

  const float Dn = Dv[n];
  const float* Zb = zs + (size_t)(b * kL + l0) * kDI + n * 64 + d;
  _Float16* Yb = yin + (size_t)(b * kL + l0) * kDI + n * 64 + d;

  float cz = Zb[0];
  __syncthreads();

#pragma unroll 4
  for (int t = 0; t < kQ; ++t) {
    const int tp = (t + 1 < kQ) ? (t + 1) : (kQ - 1);
    const float nz = Zb[(size_t)tp * kDI];

    f4 a[4], bb[4], cf[4];
#pragma unroll
    for (int j = 0; j < 4; ++j) {
      a[j]  = ((const f4*)&Ad[t][sg * 16])[j];
      bb[j] = ((const f4*)&Bd[t][sg * 16])[j];
      cf[j] = ((const f4*)&Cd[t][sg * 16])[j];
    }
    const float xt = Xd[t][d];

    float pq[4];
#pragma unroll
    for (int q = 0; q < 4; ++q) {
      float p = 0.f;
#pragma unroll
      for (int j = 0; j < 4; ++j) {
        h[q * 4 + j] = a[q][j] * h[q * 4 + j] + bb[q][j] * xt;
        p += cf[q][j] * h[q * 4 + j];
      }
      pq[q] = p;
    }
    float p = (pq[0] + pq[1]) + (pq[2] + pq[3]);
    p += __shfl_xor(p, 16);
    p += __shfl_xor(p, 32);
    if (sg == 0)
      Yb[(size_t)t * kDI] = (_Float16)((p + Dn * xt) * cz);
    cz = nz;
  }
}

// ---------------------------------------------------------------------------
extern "C" void kernel_launch(void* const* d_in, const int* in_sizes, int n_in,
                              void* d_out, int out_size, void* d_ws, size_t ws_size,
                              hipStream_t stream) {
  const float* x      = (const float*)d_in[0];
  const float* W_in   = (const float*)d_in[1];
  const float* conv_w = (const float*)d_in[2];
  const float* conv_b = (const float*)d_in[3];
  const float* A_log  = (const float*)d_in[4];
  const float* Dv     = (const float*)d_in[5];
  const float* dt_b   = (const float*)d_in[6];
  const float* W_out  = (const float*)d_in[7];
  float* out = (float*)d_out;

  char* p = (char*)d_ws;
  float* proj  = (float*)p; p += (size_t)kBL * kDPROJ * 4;       // 67.4 MB
  float* xconv = (float*)p; p += (size_t)kBL * kDI * 4;          // 16.8 MB
  float* zsb   = (float*)p; p += (size_t)kBL * kDI * 4;          // 16.8 MB
  float* dtb   = (float*)p; p += (size_t)64 * kL * 4;            // 0.26 MB
  float* sdt   = (float*)p; p += (size_t)64 * kNC * 4 + 4032;    // pad to 16B
  float* hloc  = (float*)p; p += (size_t)64 * kNC * 64 * 64 * 4; // 16.8 MB
  float* hin   = (float*)p; p += (size_t)64 * kNC * 64 * 64 * 4; // 16.8 MB
  _Float16* yin  = (_Float16*)p; p += (size_t)kBL * kDI * 2;     // 8.4 MB
  _Float16* Wo16 = (_Float16*)p; p += (size_t)kDM * kDI * 2;     // 4.2 MB
  // union 1: x16/Wi16 (GEMM1 phase) alias hloc+hin (scan phase)
  _Float16* x16  = (_Float16*)hloc;                  // 4.2 MB
  _Float16* Wi16 = x16 + (size_t)kBL * kDM;          // 16.8 MB (spills into hin)
  // union 2: dA/dB/Cpk (scan phase) alias split-K partials (GEMM2 phase)
  char* u = p;
  float* dA  = (float*)u;
  float* dB  = dA + (size_t)64 * kL * 64;
  float* Cpk = dB + (size_t)64 * kL * 64;            // trio = 50.3 MB
  float* parts = (float*)u;                          // 4 x 8.4 = 33.6 MB

  const int n0 = kBL * kDM / 4;     // x      vec4 count
  const int n1 = kDPROJ * kDM / 4;  // W_in
  const int n2 = kDM * kDI / 4;     // W_out
  cvt_all<<<(n0 + n1 + n2 + 255) / 256, 256, 0, stream>>>(
      x, x16, n0, W_in, Wi16, n1, W_out, Wo16, n2);

  gemm_bt16<<<dim3(kBL / 128, (kDPROJ + 127) / 128, 1), 256, 0, stream>>>(
      x16, Wi16, proj, kBL, kDPROJ, kDM, kDM, kDM);

  prep_conv<<<(kBL * kDI) / 256, 256, 0, stream>>>(proj, conv_w, conv_b, xconv, zsb);
  prep_scan<<<(64 * kL * 64) / 256, 256, 0, stream>>>(proj, A_log, dt_b, dA, dB, Cpk, dtb);
  scan_pass1<<<64 * kNC, 256, 0, stream>>>(dA, dB, xconv, dtb, hloc, sdt);
  scan_pass2<<<64, 256, 0, stream>>>(hloc, sdt, A_log, hin);
  scan_pass3<<<64 * kNC, 256, 0, stream>>>(dA, dB, Cpk, xconv, hin, zsb, Dv, yin);

  // GEMM2 split-K=4: 512 blocks (2/CU), then reduce
  gemm_bt16<<<dim3(kBL / 128, kDM / 128, 4), 256, 0, stream>>>(
      yin, Wo16, parts, kBL, kDM, kDI / 4, kDI, kDI);
  add4<<<(kBL * kDM / 4 + 255) / 256, 256, 0, stream>>>(parts, out, kBL * kDM / 4);
}

// Round 5
// 321.518 us; speedup vs baseline: 1.6287x; 1.0280x over previous
//
#include <hip/hip_runtime.h>
#include <hip/hip_fp16.h>
#include <type_traits>

namespace {
constexpr int kB  = 2;
constexpr int kL  = 1024;
constexpr int kDM = 1024;
constexpr int kDI = 2048;
constexpr int kDPROJ = 2 * kDI + 32 * (2 * 64 + 1);  // 8224
constexpr int kBL = kB * kL;                          // 2048
constexpr int kQ  = 64;                               // chunk length
constexpr int kNC = kL / kQ;                          // 16 chunks
}

typedef float f4 __attribute__((ext_vector_type(4)));
typedef _Float16 f16x8 __attribute__((ext_vector_type(8)));
typedef _Float16 f16x4 __attribute__((ext_vector_type(4)));

__device__ __forceinline__ void async_ld16(const void* g, void* l) {
  __builtin_amdgcn_global_load_lds(
      (const __attribute__((address_space(1))) void*)g,
      (__attribute__((address_space(3))) void*)l, 16, 0, 0);
}

// ---------------------------------------------------------------------------
// Fused f32 -> f16 conversion of x, W_in, W_out (vectorized x4)
// ---------------------------------------------------------------------------
__global__ __launch_bounds__(256) void cvt_all(
    const float* __restrict__ s0, _Float16* __restrict__ d0, int n0,
    const float* __restrict__ s1, _Float16* __restrict__ d1, int n1,
    const float* __restrict__ s2, _Float16* __restrict__ d2, int n2) {
  int i = blockIdx.x * 256 + threadIdx.x;  // vec4 index
  const float* s; _Float16* d;
  if (i < n0) { s = s0; d = d0; }
  else if (i < n0 + n1) { s = s1; d = d1; i -= n0; }
  else if (i < n0 + n1 + n2) { s = s2; d = d2; i -= n0 + n1; }
  else return;
  const f4 v = ((const f4*)s)[i];
  f16x4 o;
  o[0] = (_Float16)v[0]; o[1] = (_Float16)v[1];
  o[2] = (_Float16)v[2]; o[3] = (_Float16)v[3];
  ((f16x4*)d)[i] = o;
}

// ---------------------------------------------------------------------------
// f16 GEMM, BK=64, XOR-swizzled LDS (conflict-free fragment reads while
// keeping global_load_lds's base+lane*16 dest mapping).
// C[M,N] = A[M,*] @ B[N,*]^T over K cols at blockIdx.z*K (split-K).
// OutT: _Float16 (proj) or float (split-K partials).
// kDtSidecar: also write f32 dt columns (gn-4096 % 129 == 128) to dtcol.
// ---------------------------------------------------------------------------
template <typename OutT, bool kDtSidecar>
__global__ __launch_bounds__(256) void gemm_bt16(
    const _Float16* __restrict__ A, const _Float16* __restrict__ Bm,
    OutT* __restrict__ C, float* __restrict__ dtcol,
    int M, int N, int K, int lda, int ldb) {
  __shared__ alignas(16) _Float16 As[128][64];
  __shared__ alignas(16) _Float16 Bs[128][64];
  const int tid  = threadIdx.x;
  const int lane = tid & 63;
  const int w    = tid >> 6;
  const int m0   = blockIdx.x * 128;
  const int n0   = blockIdx.y * 128;
  const int r8   = lane >> 3;   // row within 8-row group
  const int c8   = lane & 7;    // 16B chunk within 128B row
  const int wm   = (w & 1) * 64;
  const int wn   = (w >> 1) * 64;
  const int l16  = lane & 15;
  const int l4   = lane >> 4;

  A  += (size_t)blockIdx.z * K;
  Bm += (size_t)blockIdx.z * K;
  C  += (size_t)blockIdx.z * M * N;

  const int g = c8 ^ r8;  // swizzle: global chunk g lands at lds chunk c8

  f4 acc[4][4] = {};

  for (int k0 = 0; k0 < K; k0 += 64) {
#pragma unroll
    for (int q = 0; q < 4; ++q) {
      const int row = (w * 4 + q) * 8 + r8;
      async_ld16(A + (size_t)(m0 + row) * lda + k0 + g * 8, &As[row][c8 * 8]);
      int gn = n0 + row;
      gn = gn < N ? gn : N - 1;  // clamp partial N tile (valid memory)
      async_ld16(Bm + (size_t)gn * ldb + k0 + g * 8, &Bs[row][c8 * 8]);
    }
    __syncthreads();
#pragma unroll
    for (int kk = 0; kk < 2; ++kk) {
      f16x8 af[4], bf[4];
      const int swz = (l4 + 4 * kk) ^ (l16 & 7);
#pragma unroll
      for (int t = 0; t < 4; ++t) {
        af[t] = *reinterpret_cast<const f16x8*>(
            (const char*)&As[0][0] + (size_t)(wm + t * 16 + l16) * 128 + swz * 16);
        bf[t] = *reinterpret_cast<const f16x8*>(
            (const char*)&Bs[0][0] + (size_t)(wn + t * 16 + l16) * 128 + swz * 16);
      }
#pragma unroll
      for (int i = 0; i < 4; ++i)
#pragma unroll
        for (int j = 0; j < 4; ++j)
          acc[i][j] = __builtin_amdgcn_mfma_f32_16x16x32_f16(af[i], bf[j], acc[i][j], 0, 0, 0);
    }
    __syncthreads();
  }

  // C/D layout: col = lane&15, row = (lane>>4)*4 + reg
  const int col = l16;
  const int r0  = l4 * 4;
#pragma unroll
  for (int i = 0; i < 4; ++i)
#pragma unroll
    for (int j = 0; j < 4; ++j) {
      const int gn = n0 + wn + j * 16 + col;
      if (gn >= N) continue;
#pragma unroll
      for (int r = 0; r < 4; ++r) {
        const int gm = m0 + wm + i * 16 + r0 + r;
        if constexpr (std::is_same_v<OutT, float>)
          C[(size_t)gm * N + gn] = acc[i][j][r];
        else
          C[(size_t)gm * N + gn] = (_Float16)acc[i][j][r];
      }
      if constexpr (kDtSidecar) {
        const int rr = gn - 2 * kDI;
        if (rr >= 0 && rr % 129 == 128) {
          const int head = rr / 129;
#pragma unroll
          for (int r = 0; r < 4; ++r) {
            const int gm = m0 + wm + i * 16 + r0 + r;
            dtcol[(size_t)gm * 32 + head] = acc[i][j][r];
          }
        }
      }
    }
}

// ---------------------------------------------------------------------------
// out = p0 + p1 + p2 + p3 (split-K reduction), vectorized x4
// ---------------------------------------------------------------------------
__global__ __launch_bounds__(256) void add4(
    const float* __restrict__ parts, float* __restrict__ out, int n4) {
  const int i = blockIdx.x * 256 + threadIdx.x;
  if (i >= n4) return;
  const size_t mn4 = (size_t)kBL * kDM / 4;
  const f4* p = (const f4*)parts;
  const f4 v = p[i] + p[i + mn4] + p[i + 2 * mn4] + p[i + 3 * mn4];
  ((f4*)out)[i] = v;
}

// ---------------------------------------------------------------------------
// Depthwise causal conv(4) + bias + SiLU -> xc16; SiLU(z) -> zs16  (f16)
// ---------------------------------------------------------------------------
__global__ __launch_bounds__(256) void prep_conv(
    const _Float16* __restrict__ proj, const float* __restrict__ conv_w,
    const float* __restrict__ conv_b, _Float16* __restrict__ xconv,
    _Float16* __restrict__ zs) {
  const int idx = blockIdx.x * 256 + threadIdx.x;  // [0, kBL*kDI)
  const int d   = idx & (kDI - 1);
  const int bl  = idx >> 11;
  const int l   = bl & (kL - 1);
  float acc = conv_b[d];
#pragma unroll
  for (int j = 0; j < 4; ++j) {
    const int lj = l - 3 + j;
    if (lj >= 0)
      acc += conv_w[d * 4 + j] * (float)proj[(size_t)(bl - 3 + j) * kDPROJ + d];
  }
  xconv[idx] = (_Float16)(acc / (1.f + __expf(-acc)));
  const float z = (float)proj[(size_t)bl * kDPROJ + kDI + d];
  zs[idx] = (_Float16)(z / (1.f + __expf(-z)));
}

// ---------------------------------------------------------------------------
// dt = softplus(dtcol + bias); dA = exp(A*dt); dB = B*dt; Cpk = packed C
// layouts: dA/dB/Cpk [bn][l][s] f32 (s contiguous), dtb [bn][l]
// ---------------------------------------------------------------------------
__global__ __launch_bounds__(256) void prep_scan(
    const _Float16* __restrict__ proj, const float* __restrict__ dtcol,
    const float* __restrict__ A_log, const float* __restrict__ dt_bias,
    float* __restrict__ dA, float* __restrict__ dB, float* __restrict__ Cpk,
    float* __restrict__ dtb) {
  const int idx = blockIdx.x * 256 + threadIdx.x;  // [0, 64*kL*64)
  const int s   = idx & 63;
  const int t   = idx >> 6;  // bn*kL + l
  const int l   = t & (kL - 1);
  const int bn  = t >> 10;
  const int n   = bn & 31;
  const int b   = bn >> 5;
  const size_t prow = (size_t)(b * kL + l) * kDPROJ + 2 * kDI + n * 129;
  const float dtp = dtcol[(size_t)(b * kL + l) * 32 + n] + dt_bias[n];
  const float dt  = (dtp > 20.f) ? dtp : log1pf(__expf(dtp));
  const float Aa  = -__expf(A_log[n * 64 + s]);
  dA[idx]  = __expf(Aa * dt);
  dB[idx]  = (float)proj[prow + s] * dt;
  Cpk[idx] = (float)proj[prow + 64 + s];
  if (s == 0) dtb[t] = dt;
}

// ---------------------------------------------------------------------------
// Scan pass 1 (LDS-staged): stage chunk dA/dB (f32) + x (f16) into LDS, run
// the 64-step recurrence. lane = d, wave w owns s in [16w, 16w+16).
// ---------------------------------------------------------------------------
__global__ __launch_bounds__(256) void scan_pass1(
    const float* __restrict__ dA, const float* __restrict__ dB,
    const _Float16* __restrict__ xconv, const float* __restrict__ dtb,
    float* __restrict__ hloc, float* __restrict__ sdt) {
  __shared__ alignas(16) float Ad[kQ][64];      // 16 KB
  __shared__ alignas(16) float Bd[kQ][64];      // 16 KB
  __shared__ alignas(16) _Float16 Xd[kQ][64];   // 8 KB
  __shared__ alignas(16) float dts[kQ];         // 256 B
  const int tid  = threadIdx.x;
  const int bn   = blockIdx.x >> 4;
  const int c    = blockIdx.x & (kNC - 1);
  const int lane = tid & 63;
  const int w    = tid >> 6;
  const int b    = bn >> 5, n = bn & 31;
  const int l0   = c * kQ;

  const float* gA = dA + ((size_t)bn * kL + l0) * 64;
  const float* gB = dB + ((size_t)bn * kL + l0) * 64;
#pragma unroll
  for (int i = 0; i < 4; ++i) {
    async_ld16(gA + i * 1024 + tid * 4, &Ad[0][0] + i * 1024 + tid * 4);
    async_ld16(gB + i * 1024 + tid * 4, &Bd[0][0] + i * 1024 + tid * 4);
  }
  // x rows: 64 rows x 128B (f16); 8 lanes x 16B per row
#pragma unroll
  for (int i = 0; i < 2; ++i) {
    const int t = i * 32 + (tid >> 3);
    const int cc = (tid & 7) * 8;
    async_ld16(xconv + (size_t)(b * kL + l0 + t) * kDI + n * 64 + cc, &Xd[t][cc]);
  }
  if (tid < 16) async_ld16(dtb + (size_t)bn * kL + l0 + tid * 4, &dts[tid * 4]);
  __syncthreads();

  if (tid == 0) {
    float s = 0.f;
    for (int t = 0; t < kQ; ++t) s += dts[t];
    sdt[bn * kNC + c] = s;
  }

  float h[16];
#pragma unroll
  for (int j = 0; j < 16; ++j) h[j] = 0.f;

#pragma unroll 4
  for (int t = 0; t < kQ; ++t) {
    f4 a[4], bb[4];
#pragma unroll
    for (int j = 0; j < 4; ++j) {
      a[j]  = ((const f4*)&Ad[t][w * 16])[j];
      bb[j] = ((const f4*)&Bd[t][w * 16])[j];
    }
    const float xt = (float)Xd[t][lane];
#pragma unroll
    for (int q = 0; q < 4; ++q)
#pragma unroll
      for (int j = 0; j < 4; ++j)
        h[q * 4 + j] = a[q][j] * h[q * 4 + j] + bb[q][j] * xt;
  }

  float* hp = hloc + (((size_t)bn * kNC + c) * 64 + w * 16) * 64 + lane;
#pragma unroll
  for (int j = 0; j < 16; ++j) hp[(size_t)j * 64] = h[j];
}

// ---------------------------------------------------------------------------
// Scan pass 2: chunk stitching, 256 blocks: bn = blk>>2, d-slice = blk&3.
// h_in[c+1] = exp(A_s * sdt[c]) * h_in[c] + hloc[c]
// ---------------------------------------------------------------------------
__global__ __launch_bounds__(256) void scan_pass2(
    const float* __restrict__ hloc, const float* __restrict__ sdt,
    const float* __restrict__ A_log, float* __restrict__ hin) {
  const int bn = blockIdx.x >> 2;
  const int dq = blockIdx.x & 3;
  const int n  = bn & 31;
  const int s  = threadIdx.x >> 2;
  const int d0 = dq * 16 + (threadIdx.x & 3) * 4;
  const float Aa = -__expf(A_log[n * 64 + s]);
  f4 h = {};
  for (int c = 0; c < kNC; ++c) {
    const size_t off = (((size_t)bn * kNC + c) * 64 + s) * 64 + d0;
    const float ap = __expf(Aa * sdt[bn * kNC + c]);
    *(f4*)(hin + off) = h;
    h = ap * h + *(const f4*)(hloc + off);
  }
}

// ---------------------------------------------------------------------------
// Scan pass 3 (fully LDS-staged): dA/dB/C f32 + x/z f16 in LDS; recurrence
// from h_in; per-step s-reduction via shfl; yin = (y + D*x) * silu(z) (f16).
// lanes = (sg, dd): sg = s-group (4x16), dd = d; d = w*16 + dd.
// ---------------------------------------------------------------------------
__global__ __launch_bounds__(256) void scan_pass3(
    const float* __restrict__ dA, const float* __restrict__ dB,
    const float* __restrict__ Cpk, const _Float16* __restrict__ xconv,
    const float* __restrict__ hin, const _Float16* __restrict__ zs,
    const float* __restrict__ Dv, _Float16* __restrict__ yin) {
  __shared__ alignas(16) float Ad[kQ][64];      // 16 KB
  __shared__ alignas(16) float Bd[kQ][64];      // 16 KB
  __shared__ alignas(16) float Cd[kQ][64];      // 16 KB
  __shared__ alignas(16) _Float16 Xd[kQ][64];   // 8 KB
  __shared__ alignas(16) _Float16 Zd[kQ][64];   // 8 KB
  const int tid  = threadIdx.x;
  const int bn   = blockIdx.x >> 4;
  const int c    = blockIdx.x & (kNC - 1);
  const int lane = tid & 63;
  const int w    = tid >> 6;          // d-group
  const int sg   = lane >> 4;         // s-group
  const int dd   = lane & 15;
  const int b    = bn >> 5, n = bn & 31;
  const int l0   = c * kQ;
  const int d    = w * 16 + dd;

  const float* gA = dA + ((size_t)bn * kL + l0) * 64;
  const float* gB = dB + ((size_t)bn * kL + l0) * 64;
  const float* gC = Cpk + ((size_t)bn * kL + l0) * 64;
#pragma unroll
  for (int i = 0; i < 4; ++i) {
    async_ld16(gA + i * 1024 + tid * 4, &Ad[0][0] + i * 1024 + tid * 4);
    async_ld16(gB + i * 1024 + tid * 4, &Bd[0][0] + i * 1024 + tid * 4);
    async_ld16(gC + i * 1024 + tid * 4, &Cd[0][0] + i * 1024 + tid * 4);
  }
#pragma unroll
  for (int i = 0; i < 2; ++i) {
    const int t = i * 32 + (tid >> 3);
    const int cc = (tid & 7) * 8;
    const size_t goff = (size_t)(b * kL + l0 + t) * kDI + n * 64 + cc;
    async_ld16(xconv + goff, &Xd[t][cc]);
    async_ld16(zs + goff, &Zd[t][cc]);
  }

  // h init (global, overlaps staging)
  float h[16];
  const float* hp = hin + (((size_t)bn * kNC + c) * 64 + sg * 16) * 64 + d;
#pragma unroll
  for (int j = 0; j < 16; ++j) h[j] = hp[(size_t)j * 64];

  const float Dn = Dv[n];
  _Float16* Yb = yin + (size_t)(b * kL + l0) * kDI + n * 64 + d;
  __syncthreads();

#pragma unroll 4
  for (int t = 0; t < kQ; ++t) {
    f4 a[4], bb[4], cf[4];
#pragma unroll
    for (int j = 0; j < 4; ++j) {
      a[j]  = ((const f4*)&Ad[t][sg * 16])[j];
      bb[j] = ((const f4*)&Bd[t][sg * 16])[j];
      cf[j] = ((const f4*)&Cd[t][sg * 16])[j];
    }
    const float xt = (float)Xd[t][d];

    float pq[4];
#pragma unroll
    for (int q = 0; q < 4; ++q) {
      float p = 0.f;
#pragma unroll
      for (int j = 0; j < 4; ++j) {
        h[q * 4 + j] = a[q][j] * h[q * 4 + j] + bb[q][j] * xt;
        p += cf[q][j] * h[q * 4 + j];
      }
      pq[q] = p;
    }
    float p = (pq[0] + pq[1]) + (pq[2] + pq[3]);
    p += __shfl_xor(p, 16);
    p += __shfl_xor(p, 32);
    if (sg == 0)
      Yb[(size_t)t * kDI] = (_Float16)((p + Dn * xt) * (float)Zd[t][d]);
  }
}

// ---------------------------------------------------------------------------
extern "C" void kernel_launch(void* const* d_in, const int* in_sizes, int n_in,
                              void* d_out, int out_size, void* d_ws, size_t ws_size,
                              hipStream_t stream) {
  const float* x      = (const float*)d_in[0];
  const float* W_in   = (const float*)d_in[1];
  const float* conv_w = (const float*)d_in[2];
  const float* conv_b = (const float*)d_in[3];
  const float* A_log  = (const float*)d_in[4];
  const float* Dv     = (const float*)d_in[5];
  const float* dt_b   = (const float*)d_in[6];
  const float* W_out  = (const float*)d_in[7];
  float* out = (float*)d_out;

  char* p = (char*)d_ws;
  _Float16* proj16 = (_Float16*)p; p += (size_t)kBL * kDPROJ * 2;   // 33.7 MB
  float* dtcol = (float*)p; p += (size_t)kBL * 32 * 4;              // 0.26 MB
  _Float16* xc16 = (_Float16*)p; p += (size_t)kBL * kDI * 2;        // 8.4 MB
  _Float16* zs16 = (_Float16*)p; p += (size_t)kBL * kDI * 2;        // 8.4 MB
  float* dtb   = (float*)p; p += (size_t)64 * kL * 4;               // 0.26 MB
  float* sdt   = (float*)p; p += (size_t)64 * kNC * 4 + 4032;       // pad
  float* hloc  = (float*)p; p += (size_t)64 * kNC * 64 * 64 * 4;    // 16.8 MB
  float* hin   = (float*)p; p += (size_t)64 * kNC * 64 * 64 * 4;    // 16.8 MB
  _Float16* yin  = (_Float16*)p; p += (size_t)kBL * kDI * 2;        // 8.4 MB
  _Float16* Wo16 = (_Float16*)p; p += (size_t)kDM * kDI * 2;        // 4.2 MB
  // union 1: x16/Wi16 (GEMM1 phase) alias hloc+hin (scan phase)
  _Float16* x16  = (_Float16*)hloc;                  // 4.2 MB
  _Float16* Wi16 = x16 + (size_t)kBL * kDM;          // 16.8 MB (spills into hin)
  // union 2: dA/dB/Cpk f32 (scan phase) alias split-K partials (GEMM2 phase)
  char* u = p;
  float* dA  = (float*)u;
  float* dB  = dA + (size_t)64 * kL * 64;
  float* Cpk = dB + (size_t)64 * kL * 64;            // trio = 50.3 MB
  float* parts = (float*)u;                          // 4 x 8.4 = 33.6 MB

  const int n0 = kBL * kDM / 4;     // x      vec4 count
  const int n1 = kDPROJ * kDM / 4;  // W_in
  const int n2 = kDM * kDI / 4;     // W_out
  cvt_all<<<(n0 + n1 + n2 + 255) / 256, 256, 0, stream>>>(
      x, x16, n0, W_in, Wi16, n1, W_out, Wo16, n2);

  gemm_bt16<_Float16, true><<<dim3(kBL / 128, (kDPROJ + 127) / 128, 1), 256, 0, stream>>>(
      x16, Wi16, proj16, dtcol, kBL, kDPROJ, kDM, kDM, kDM);

  prep_conv<<<(kBL * kDI) / 256, 256, 0, stream>>>(proj16, conv_w, conv_b, xc16, zs16);
  prep_scan<<<(64 * kL * 64) / 256, 256, 0, stream>>>(proj16, dtcol, A_log, dt_b,
                                                      dA, dB, Cpk, dtb);
  scan_pass1<<<64 * kNC, 256, 0, stream>>>(dA, dB, xc16, dtb, hloc, sdt);
  scan_pass2<<<256, 256, 0, stream>>>(hloc, sdt, A_log, hin);
  scan_pass3<<<64 * kNC, 256, 0, stream>>>(dA, dB, Cpk, xc16, hin, zs16, Dv, yin);

  // GEMM2 split-K=4: 512 blocks, then reduce
  gemm_bt16<float, false><<<dim3(kBL / 128, kDM / 128, 4), 256, 0, stream>>>(
      yin, Wo16, parts, nullptr, kBL, kDM, kDI / 4, kDI, kDI);
  add4<<<(kBL * kDM / 4 + 255) / 256, 256, 0, stream>>>(parts, out, kBL * kDM / 4);
}